// Round 3
// baseline (602.791 us; speedup 1.0000x reference)
//
#include <hip/hip_runtime.h>

#define ND 64
#define HH 128
#define WPAD 129

// ---------------- zero out output ----------------
__global__ void zero_kernel(float* __restrict__ p, int n) {
    int i = blockIdx.x * blockDim.x + threadIdx.x;
    if (i < n) p[i] = 0.f;
}

// ---------------- fused MLP forward + backward ----------------
// One wave (64 lanes) per atom. Each lane owns h-columns {lane, lane+64}.
// Weights staged in LDS with pad-129 stride: bank = (row + col) % 32 for both
// [k][lane] (forward) and [lane][k] (backward/transposed) patterns -> conflict-free.
__global__ __launch_bounds__(512, 1) void mlp_fwd_bwd(
    const float* __restrict__ x,
    const float* __restrict__ W1, const float* __restrict__ b1,
    const float* __restrict__ W2, const float* __restrict__ b2,
    const float* __restrict__ W3, const float* __restrict__ b3,
    const int* __restrict__ indices,
    float* __restrict__ energy_out, float* __restrict__ dEdD, int natoms)
{
    __shared__ float w1s[ND][WPAD];   // 33 KB
    __shared__ float w2s[HH][WPAD];   // 66 KB
    __shared__ float w3s[HH];
    __shared__ float b1s[HH];
    __shared__ float b2s[HH];

    const int tid = threadIdx.x;
    for (int idx = tid; idx < ND * HH; idx += 512) w1s[idx / HH][idx % HH] = W1[idx];
    for (int idx = tid; idx < HH * HH; idx += 512) w2s[idx / HH][idx % HH] = W2[idx];
    if (tid < HH) { w3s[tid] = W3[tid]; b1s[tid] = b1[tid]; b2s[tid] = b2[tid]; }
    __syncthreads();

    const float b3v = b3[0];
    const int lane = tid & 63;
    const int wave = tid >> 6;
    const int gwave = blockIdx.x * 8 + wave;
    const int nwaves = gridDim.x * 8;

    for (int a = gwave; a < natoms; a += nwaves) {
        const float xv = x[(long)a * ND + lane];   // lane indexes d (ND==64)

        // ---- layer 1: z1[j] = b1[j] + sum_d x[d]*W1[d][j] ----
        float z1a = b1s[lane], z1b = b1s[lane + 64];
        #pragma unroll
        for (int d = 0; d < ND; ++d) {
            const float xd_ = __shfl(xv, d);
            z1a += xd_ * w1s[d][lane];
            z1b += xd_ * w1s[d][lane + 64];
        }
        const float h1a = 1.f / (1.f + expf(-z1a));
        const float h1b = 1.f / (1.f + expf(-z1b));

        // ---- layer 2: z2[j] = b2[j] + sum_k h1[k]*W2[k][j] ----
        float z2a = b2s[lane], z2b = b2s[lane + 64];
        #pragma unroll
        for (int k = 0; k < 64; ++k) {
            const float hk = __shfl(h1a, k);
            z2a += hk * w2s[k][lane];
            z2b += hk * w2s[k][lane + 64];
        }
        #pragma unroll
        for (int k = 0; k < 64; ++k) {
            const float hk = __shfl(h1b, k);
            z2a += hk * w2s[64 + k][lane];
            z2b += hk * w2s[64 + k][lane + 64];
        }
        const float h2a = 1.f / (1.f + expf(-z2a));
        const float h2b = 1.f / (1.f + expf(-z2b));

        // ---- energy: E = sum_j h2[j]*W3[j] + b3 ----
        float part = h2a * w3s[lane] + h2b * w3s[lane + 64];
        #pragma unroll
        for (int off = 32; off > 0; off >>= 1) part += __shfl_xor(part, off);
        if (lane == 0) atomicAdd(&energy_out[indices[a]], part + b3v);

        // ---- backward ----
        // dE/dz2[j] = W3[j] * h2[j](1-h2[j])
        const float g2a = w3s[lane]      * h2a * (1.f - h2a);
        const float g2b = w3s[lane + 64] * h2b * (1.f - h2b);

        // dh1[k] = sum_j g2[j]*W2[k][j]  (lane owns k=lane, k=lane+64)
        float d1a = 0.f, d1b = 0.f;
        #pragma unroll
        for (int j = 0; j < 64; ++j) {
            const float g = __shfl(g2a, j);
            d1a += g * w2s[lane][j];
            d1b += g * w2s[lane + 64][j];
        }
        #pragma unroll
        for (int j = 0; j < 64; ++j) {
            const float g = __shfl(g2b, j);
            d1a += g * w2s[lane][64 + j];
            d1b += g * w2s[lane + 64][64 + j];
        }
        const float dz1a = d1a * h1a * (1.f - h1a);
        const float dz1b = d1b * h1b * (1.f - h1b);

        // dEdD[d] = sum_k dz1[k]*W1[d][k]  (lane owns d=lane, d<64)
        float dd = 0.f;
        #pragma unroll
        for (int k = 0; k < 64; ++k) {
            const float g = __shfl(dz1a, k);
            dd += g * w1s[lane][k];
        }
        #pragma unroll
        for (int k = 0; k < 64; ++k) {
            const float g = __shfl(dz1b, k);
            dd += g * w1s[lane][64 + k];
        }
        dEdD[(long)a * ND + lane] = dd;
    }
}

// ---------------- force accumulation ----------------
// 16 lanes per row, 4 rows per wave. xd streamed with float4 (fully coalesced),
// dEdD gathered from L2/LLC (5 MB resident). One atomicAdd per row.
__global__ __launch_bounds__(256) void force_kernel(
    const float* __restrict__ xd,
    const int* __restrict__ unique_i, const int* __restrict__ unique_j,
    const float* __restrict__ dEdD,
    float* __restrict__ forces, int nderiv)
{
    const int tid = threadIdx.x;
    const int lane = tid & 63;
    const int wib = tid >> 6;
    const int gwave = blockIdx.x * 4 + wib;
    const int nwaves = gridDim.x * 4;
    const int sub = lane >> 4;   // row within group: 0..3
    const int t = lane & 15;     // quad within row: 0..15
    const int ngroups = (nderiv + 3) >> 2;

    for (int g = gwave; g < ngroups; g += nwaves) {
        const int r = g * 4 + sub;
        float p = 0.f;
        int jdst = 0, ax = 0;
        const bool valid = (r < nderiv);
        if (valid) {
            const int ai = unique_i[r];
            const float4 v = ((const float4*)(xd   + (long)r  * 64))[t];
            const float4 w = ((const float4*)(dEdD + (long)ai * 64))[t];
            p = v.x * w.x + v.y * w.y + v.z * w.z + v.w * w.w;
            jdst = unique_j[r];
            ax = r % 3;           // axis pattern is tile([0,1,2]) by construction
        }
        p += __shfl_xor(p, 1);
        p += __shfl_xor(p, 2);
        p += __shfl_xor(p, 4);
        p += __shfl_xor(p, 8);
        if (t == 0 && valid) atomicAdd(&forces[jdst * 3 + ax], p);
    }
}

extern "C" void kernel_launch(void* const* d_in, const int* in_sizes, int n_in,
                              void* d_out, int out_size, void* d_ws, size_t ws_size,
                              hipStream_t stream) {
    const float* x        = (const float*)d_in[0];
    const float* xd       = (const float*)d_in[1];
    const int*   indices  = (const int*)d_in[2];
    // d_in[3] atoms_per_structure, d_in[4] types, d_in[5] xd_indx: unused
    const int*   unique_i = (const int*)d_in[6];
    const int*   unique_j = (const int*)d_in[7];
    const float* W1       = (const float*)d_in[8];
    const float* b1       = (const float*)d_in[9];
    const float* W2       = (const float*)d_in[10];
    const float* b2       = (const float*)d_in[11];
    const float* W3       = (const float*)d_in[12];
    const float* b3       = (const float*)d_in[13];

    const int natoms = in_sizes[2];   // indices has NATOMS entries
    const int nconf  = in_sizes[3];
    const int nderiv = in_sizes[6];   // unique_i has NDERIV entries

    float* out    = (float*)d_out;
    float* energy = out;              // [nconf]
    float* forces = out + nconf;      // [3*natoms]
    float* dEdD   = (float*)d_ws;     // natoms*ND floats (5.1 MB)

    zero_kernel<<<(out_size + 255) / 256, 256, 0, stream>>>(out, out_size);
    mlp_fwd_bwd<<<256, 512, 0, stream>>>(x, W1, b1, W2, b2, W3, b3,
                                         indices, energy, dEdD, natoms);
    force_kernel<<<2048, 256, 0, stream>>>(xd, unique_i, unique_j, dEdD,
                                           forces, nderiv);
}

// Round 4
// 169.287 us; speedup vs baseline: 3.5608x; 3.5608x over previous
//
#include <hip/hip_runtime.h>

#define TT 32   // atoms per tile

// ---------------- zero out output ----------------
__global__ void zero_kernel(float* __restrict__ p, int n) {
    int i = blockIdx.x * blockDim.x + threadIdx.x;
    if (i < n) p[i] = 0.f;
}

__device__ __forceinline__ float sigm(float z) { return 1.f / (1.f + expf(-z)); }

__device__ __forceinline__ float f4c(const float4& v, int i) {
    switch (i) { case 0: return v.x; case 1: return v.y; case 2: return v.z; default: return v.w; }
}

// ---------------- fused MLP forward + backward (tile GEMM) ----------------
// One block = one 32-atom tile. 256 threads.
// Weights are read from GLOBAL (L1/L2-cached) -> off the LDS pipe.
// Activations live in LDS, XOR-swizzled by chunk: chunk' = chunk ^ ((row>>1)&7)
// so 4-distinct-row b128 broadcasts are bank-conflict-free.
// Thread tiles: fwd (jb=tid&15 -> 8 j's, arow=tid>>4 -> 2 atoms);
// bwd phases remap so the 8-wide weight-row index is tid>>4 (coalesced loads).
__global__ __launch_bounds__(256, 4) void mlp_fwd_bwd(
    const float* __restrict__ x,
    const float* __restrict__ W1, const float* __restrict__ b1,
    const float* __restrict__ W2, const float* __restrict__ b2,
    const float* __restrict__ W3, const float* __restrict__ b3,
    const int* __restrict__ indices,
    float* __restrict__ energy_out, float* __restrict__ dEdD, int natoms)
{
    __shared__ float h1s[TT * 128];  // 16 KB: h1, later overwritten in-place with dz1
    __shared__ float Ss[TT * 128];   // 16 KB: xs (stride 64), later g2 (stride 128)

    const int tid  = threadIdx.x;
    const int jb   = tid & 15;   // 8-wide j-block
    const int arow = tid >> 4;   // atom pair
    const int a0   = blockIdx.x * TT;
    const int j0   = jb * 8;

    // per-thread bias / W3 fragments (8 j's)
    float bb1[8], bb2[8], ww3[8];
    {
        float4 t0 = *(const float4*)(b1 + j0), t1 = *(const float4*)(b1 + j0 + 4);
        float4 u0 = *(const float4*)(b2 + j0), u1 = *(const float4*)(b2 + j0 + 4);
        float4 v0 = *(const float4*)(W3 + j0), v1 = *(const float4*)(W3 + j0 + 4);
        #pragma unroll
        for (int q = 0; q < 4; ++q) {
            bb1[q] = f4c(t0, q); bb1[4+q] = f4c(t1, q);
            bb2[q] = f4c(u0, q); bb2[4+q] = f4c(u1, q);
            ww3[q] = f4c(v0, q); ww3[4+q] = f4c(v1, q);
        }
    }
    const float b3v = b3[0];

    // ---- stage x tile into Ss (row stride 64 floats = 16 chunks), swizzled ----
    #pragma unroll
    for (int p = 0; p < 2; ++p) {
        int fc = tid + p * 256;            // 512 chunks total (32 rows x 16)
        int r = fc >> 4, c4 = fc & 15;
        int a = a0 + r;
        float4 v = make_float4(0.f, 0.f, 0.f, 0.f);
        if (a < natoms) v = *(const float4*)(x + (size_t)a * 64 + c4 * 4);
        *(float4*)(Ss + r * 64 + ((c4 ^ ((r >> 1) & 7)) << 2)) = v;
    }
    __syncthreads();

    // ---- layer 1: z1[a][j] = b1 + sum_d xs[a][d] * W1[d][j] ----
    float acc[2][8];
    #pragma unroll
    for (int i = 0; i < 2; ++i)
        #pragma unroll
        for (int q = 0; q < 8; ++q) acc[i][q] = bb1[q];

    #pragma unroll 2
    for (int d0 = 0; d0 < 64; d0 += 4) {
        float4 xa[2];
        #pragma unroll
        for (int i = 0; i < 2; ++i) {
            int r = 2 * arow + i;
            xa[i] = *(const float4*)(Ss + r * 64 + (((d0 >> 2) ^ ((r >> 1) & 7)) << 2));
        }
        float4 wv[4][2];
        #pragma unroll
        for (int d = 0; d < 4; ++d) {
            const float* wp = W1 + (size_t)(d0 + d) * 128 + j0;
            wv[d][0] = *(const float4*)(wp);
            wv[d][1] = *(const float4*)(wp + 4);
        }
        #pragma unroll
        for (int i = 0; i < 2; ++i)
            #pragma unroll
            for (int d = 0; d < 4; ++d) {
                float xv = f4c(xa[i], d);
                #pragma unroll
                for (int q = 0; q < 4; ++q) {
                    acc[i][q]     += xv * f4c(wv[d][0], q);
                    acc[i][4 + q] += xv * f4c(wv[d][1], q);
                }
            }
    }
    // sigmoid -> h1s (swizzled)
    #pragma unroll
    for (int i = 0; i < 2; ++i) {
        int r = 2 * arow + i, key = (r >> 1) & 7;
        float4 h0, h1v;
        h0.x = sigm(acc[i][0]); h0.y = sigm(acc[i][1]); h0.z = sigm(acc[i][2]); h0.w = sigm(acc[i][3]);
        h1v.x = sigm(acc[i][4]); h1v.y = sigm(acc[i][5]); h1v.z = sigm(acc[i][6]); h1v.w = sigm(acc[i][7]);
        *(float4*)(h1s + r * 128 + (((2 * jb) ^ key) << 2)) = h0;
        *(float4*)(h1s + r * 128 + (((2 * jb + 1) ^ key) << 2)) = h1v;
    }
    __syncthreads();

    // ---- layer 2: z2[a][j] = b2 + sum_k h1[a][k] * W2[k][j] ----
    #pragma unroll
    for (int i = 0; i < 2; ++i)
        #pragma unroll
        for (int q = 0; q < 8; ++q) acc[i][q] = bb2[q];

    #pragma unroll 2
    for (int k0 = 0; k0 < 128; k0 += 4) {
        float4 ha[2];
        #pragma unroll
        for (int i = 0; i < 2; ++i) {
            int r = 2 * arow + i;
            ha[i] = *(const float4*)(h1s + r * 128 + (((k0 >> 2) ^ ((r >> 1) & 7)) << 2));
        }
        float4 wv[4][2];
        #pragma unroll
        for (int d = 0; d < 4; ++d) {
            const float* wp = W2 + (size_t)(k0 + d) * 128 + j0;
            wv[d][0] = *(const float4*)(wp);
            wv[d][1] = *(const float4*)(wp + 4);
        }
        #pragma unroll
        for (int i = 0; i < 2; ++i)
            #pragma unroll
            for (int d = 0; d < 4; ++d) {
                float hv = f4c(ha[i], d);
                #pragma unroll
                for (int q = 0; q < 4; ++q) {
                    acc[i][q]     += hv * f4c(wv[d][0], q);
                    acc[i][4 + q] += hv * f4c(wv[d][1], q);
                }
            }
    }
    // h2 in regs; energy partials; g2 -> Ss (stride 128, swizzled)
    float h2v[2][8];
    #pragma unroll
    for (int i = 0; i < 2; ++i) {
        float e = 0.f;
        #pragma unroll
        for (int q = 0; q < 8; ++q) { h2v[i][q] = sigm(acc[i][q]); e += h2v[i][q] * ww3[q]; }
        e += __shfl_xor(e, 1); e += __shfl_xor(e, 2);
        e += __shfl_xor(e, 4); e += __shfl_xor(e, 8);
        if (jb == 0) {
            int a = a0 + 2 * arow + i;
            if (a < natoms) atomicAdd(&energy_out[indices[a]], e + b3v);
        }
    }
    #pragma unroll
    for (int i = 0; i < 2; ++i) {
        int r = 2 * arow + i, key = (r >> 1) & 7;
        float4 g0, g1;
        g0.x = ww3[0] * h2v[i][0] * (1.f - h2v[i][0]);
        g0.y = ww3[1] * h2v[i][1] * (1.f - h2v[i][1]);
        g0.z = ww3[2] * h2v[i][2] * (1.f - h2v[i][2]);
        g0.w = ww3[3] * h2v[i][3] * (1.f - h2v[i][3]);
        g1.x = ww3[4] * h2v[i][4] * (1.f - h2v[i][4]);
        g1.y = ww3[5] * h2v[i][5] * (1.f - h2v[i][5]);
        g1.z = ww3[6] * h2v[i][6] * (1.f - h2v[i][6]);
        g1.w = ww3[7] * h2v[i][7] * (1.f - h2v[i][7]);
        *(float4*)(Ss + r * 128 + (((2 * jb) ^ key) << 2)) = g0;
        *(float4*)(Ss + r * 128 + (((2 * jb + 1) ^ key) << 2)) = g1;
    }
    __syncthreads();

    // ---- dh1[a][k] = sum_j g2[a][j] * W2[k][j]; dz1 = dh1*h1*(1-h1) in-place ----
    {
        const int kb = tid >> 4;          // 8-wide k-block (coalesced W2 rows)
        const int m  = tid & 15;          // atom pair
        const int k0 = kb * 8;
        float acc2[2][8];
        #pragma unroll
        for (int i = 0; i < 2; ++i)
            #pragma unroll
            for (int q = 0; q < 8; ++q) acc2[i][q] = 0.f;

        #pragma unroll 2
        for (int jj = 0; jj < 128; jj += 4) {
            float4 ga[2];
            #pragma unroll
            for (int i = 0; i < 2; ++i) {
                int r = 2 * m + i;
                ga[i] = *(const float4*)(Ss + r * 128 + (((jj >> 2) ^ ((r >> 1) & 7)) << 2));
            }
            float4 wv[8];
            #pragma unroll
            for (int q = 0; q < 8; ++q)
                wv[q] = *(const float4*)(W2 + (size_t)(k0 + q) * 128 + jj);
            #pragma unroll
            for (int i = 0; i < 2; ++i)
                #pragma unroll
                for (int q = 0; q < 8; ++q)
                    #pragma unroll
                    for (int d = 0; d < 4; ++d)
                        acc2[i][q] += f4c(ga[i], d) * f4c(wv[q], d);
        }
        #pragma unroll
        for (int i = 0; i < 2; ++i) {
            int r = 2 * m + i, key = (r >> 1) & 7;
            float* pA = h1s + r * 128 + (((2 * kb) ^ key) << 2);
            float* pB = h1s + r * 128 + (((2 * kb + 1) ^ key) << 2);
            float4 hA = *(float4*)pA, hB = *(float4*)pB;
            float4 zA, zB;
            zA.x = acc2[i][0] * hA.x * (1.f - hA.x);
            zA.y = acc2[i][1] * hA.y * (1.f - hA.y);
            zA.z = acc2[i][2] * hA.z * (1.f - hA.z);
            zA.w = acc2[i][3] * hA.w * (1.f - hA.w);
            zB.x = acc2[i][4] * hB.x * (1.f - hB.x);
            zB.y = acc2[i][5] * hB.y * (1.f - hB.y);
            zB.z = acc2[i][6] * hB.z * (1.f - hB.z);
            zB.w = acc2[i][7] * hB.w * (1.f - hB.w);
            *(float4*)pA = zA; *(float4*)pB = zB;
        }
    }
    __syncthreads();

    // ---- dEdD[a][d] = sum_k dz1[a][k] * W1[d][k] ----
    {
        const int db = tid >> 4;          // 4-wide d-block (coalesced W1 rows)
        const int m  = tid & 15;          // atom pair
        const int d0 = db * 4;
        float acc3[2][4];
        #pragma unroll
        for (int i = 0; i < 2; ++i)
            #pragma unroll
            for (int q = 0; q < 4; ++q) acc3[i][q] = 0.f;

        #pragma unroll 2
        for (int k0 = 0; k0 < 128; k0 += 4) {
            float4 za[2];
            #pragma unroll
            for (int i = 0; i < 2; ++i) {
                int r = 2 * m + i;
                za[i] = *(const float4*)(h1s + r * 128 + (((k0 >> 2) ^ ((r >> 1) & 7)) << 2));
            }
            float4 wv[4];
            #pragma unroll
            for (int q = 0; q < 4; ++q)
                wv[q] = *(const float4*)(W1 + (size_t)(d0 + q) * 128 + k0);
            #pragma unroll
            for (int i = 0; i < 2; ++i)
                #pragma unroll
                for (int q = 0; q < 4; ++q)
                    #pragma unroll
                    for (int d = 0; d < 4; ++d)
                        acc3[i][q] += f4c(za[i], d) * f4c(wv[q], d);
        }
        #pragma unroll
        for (int i = 0; i < 2; ++i) {
            int a = a0 + 2 * m + i;
            if (a < natoms) {
                float4 o; o.x = acc3[i][0]; o.y = acc3[i][1]; o.z = acc3[i][2]; o.w = acc3[i][3];
                *(float4*)(dEdD + (size_t)a * 64 + d0) = o;
            }
        }
    }
}

// ---------------- force accumulation ----------------
// 16 lanes per row, 4 rows per wave. xd streamed with float4 (fully coalesced),
// dEdD gathered from L2/LLC (5 MB resident). One atomicAdd per row.
__global__ __launch_bounds__(256) void force_kernel(
    const float* __restrict__ xd,
    const int* __restrict__ unique_i, const int* __restrict__ unique_j,
    const float* __restrict__ dEdD,
    float* __restrict__ forces, int nderiv)
{
    const int tid = threadIdx.x;
    const int lane = tid & 63;
    const int wib = tid >> 6;
    const int gwave = blockIdx.x * 4 + wib;
    const int nwaves = gridDim.x * 4;
    const int sub = lane >> 4;
    const int t = lane & 15;
    const int ngroups = (nderiv + 3) >> 2;

    for (int g = gwave; g < ngroups; g += nwaves) {
        const int r = g * 4 + sub;
        float p = 0.f;
        int jdst = 0, ax = 0;
        const bool valid = (r < nderiv);
        if (valid) {
            const int ai = unique_i[r];
            const float4 v = ((const float4*)(xd   + (size_t)r  * 64))[t];
            const float4 w = ((const float4*)(dEdD + (size_t)ai * 64))[t];
            p = v.x * w.x + v.y * w.y + v.z * w.z + v.w * w.w;
            jdst = unique_j[r];
            ax = r % 3;   // axis = tile([0,1,2]) by construction
        }
        p += __shfl_xor(p, 1);
        p += __shfl_xor(p, 2);
        p += __shfl_xor(p, 4);
        p += __shfl_xor(p, 8);
        if (t == 0 && valid) atomicAdd(&forces[jdst * 3 + ax], p);
    }
}

extern "C" void kernel_launch(void* const* d_in, const int* in_sizes, int n_in,
                              void* d_out, int out_size, void* d_ws, size_t ws_size,
                              hipStream_t stream) {
    const float* x        = (const float*)d_in[0];
    const float* xd       = (const float*)d_in[1];
    const int*   indices  = (const int*)d_in[2];
    const int*   unique_i = (const int*)d_in[6];
    const int*   unique_j = (const int*)d_in[7];
    const float* W1       = (const float*)d_in[8];
    const float* b1       = (const float*)d_in[9];
    const float* W2       = (const float*)d_in[10];
    const float* b2       = (const float*)d_in[11];
    const float* W3       = (const float*)d_in[12];
    const float* b3       = (const float*)d_in[13];

    const int natoms = in_sizes[2];
    const int nconf  = in_sizes[3];
    const int nderiv = in_sizes[6];

    float* out    = (float*)d_out;
    float* energy = out;
    float* forces = out + nconf;
    float* dEdD   = (float*)d_ws;

    const int ntiles = (natoms + TT - 1) / TT;

    zero_kernel<<<(out_size + 255) / 256, 256, 0, stream>>>(out, out_size);
    mlp_fwd_bwd<<<ntiles, 256, 0, stream>>>(x, W1, b1, W2, b2, W3, b3,
                                            indices, energy, dEdD, natoms);
    force_kernel<<<2048, 256, 0, stream>>>(xd, unique_i, unique_j, dEdD,
                                           forces, nderiv);
}